// Round 2
// baseline (143.330 us; speedup 1.0000x reference)
//
#include <hip/hip_runtime.h>
#include <stdint.h>

#define BS 8192
#define DD 128
#define SPLIT 32   // column slices of 256; k_main grid = 32 row-blocks * 32 slices
#define L2E 1.4426950408889634f
#define LN2 0.6931471805599453f

typedef __attribute__((ext_vector_type(8))) short short8;
typedef __attribute__((ext_vector_type(4))) float float4v;

#if __has_builtin(__builtin_amdgcn_exp2f)
#define EXP2(x) __builtin_amdgcn_exp2f(x)
#else
#define EXP2(x) exp2f(x)
#endif

__device__ __forceinline__ float bf2f(short s) {
  union { unsigned u; float f; } c;
  c.u = ((unsigned)(unsigned short)s) << 16;
  return c.f;
}
__device__ __forceinline__ short f2bf(float f) {
  union { float f; unsigned u; } c; c.f = f;
  unsigned u = c.u + 0x7FFFu + ((c.u >> 16) & 1u);
  return (short)(u >> 16);
}

// Fragment-ordered bf16 layout ("xnbF"): 16-byte chunk index for (row, kc):
//   chunk(row,kc) = (row>>4)*256 + (kc>>2)*64 + (kc&3)*16 + (row&15)
// so a wave load F[g*256 + t*64 + lane] gives lane (quad=lane>>4, col=lane&15)
// the 8 bf16 of row g*16+col, k-chunk t*4+quad — exactly the (verified) A and B
// fragment layout of mfma_f32_16x16x32_bf16. Both A and B loads are then single
// fully-coalesced 1KB wave loads; no LDS, no barriers in k_main.

// K1: normalize rows -> xnbF (fragment-order bf16), per-class column sums (4-way
// split to cut same-address atomic chains), counts, f32 mask mf, zero-init.
// 1024 blocks (4/CU) x 8 rows; each wave handles 2 rows via float4 half-wave.
__global__ __launch_bounds__(256) void k_norm(const float* __restrict__ data,
                                              const int* __restrict__ label,
                                              char* __restrict__ xnbF,
                                              float* __restrict__ gh4,
                                              int* __restrict__ cnt,
                                              float* __restrict__ Zr,
                                              float* __restrict__ Ur,
                                              float* __restrict__ Vr,
                                              float* __restrict__ mf,
                                              float* __restrict__ out) {
  __shared__ float shg[256];
  __shared__ int shc[2];
  int tid = threadIdx.x, wave = tid >> 6, lane = tid & 63;
  int lh = lane & 31, rsel = lane >> 5;
  if (tid < 2) shc[tid] = 0;
  shg[tid] = 0.f;
  int rowbase = blockIdx.x * 8;
  if (tid < 8) {  // zero this block's accumulator rows (workspace is poisoned)
    int row = rowbase + tid;
    Zr[row] = 0.f; Ur[row] = 0.f; Vr[row] = 0.f;
    mf[row] = (label[row] == 0) ? 1.f : 0.f;
  }
  if (blockIdx.x == 0 && tid == 0) out[0] = 0.f;
  __syncthreads();

  int row = rowbase + wave * 2 + rsel;                 // 2 rows per wave
  float4 v = *(const float4*)&data[row * DD + lh * 4]; // 16B/lane, coalesced
  float ss = v.x * v.x + v.y * v.y + v.z * v.z + v.w * v.w;
#pragma unroll
  for (int off = 16; off; off >>= 1) ss += __shfl_xor(ss, off);  // 32-lane reduce
  float rn = 1.f / fmaxf(sqrtf(ss), 1e-12f);  // F.normalize eps clamp
  float x0 = v.x * rn, x1 = v.y * rn, x2 = v.z * rn, x3 = v.w * rn;

  // fragment-order bf16 store (8B per lane: two packed pairs)
  unsigned pk0 = (unsigned)(unsigned short)f2bf(x0) |
                 ((unsigned)(unsigned short)f2bf(x1) << 16);
  unsigned pk1 = (unsigned)(unsigned short)f2bf(x2) |
                 ((unsigned)(unsigned short)f2bf(x3) << 16);
  int kc = lh >> 1;
  size_t chunk = (size_t)(row >> 4) * 256 + (size_t)(kc >> 2) * 64 +
                 (size_t)(kc & 3) * 16 + (row & 15);
  *(uint2*)(xnbF + chunk * 16 + (lh & 1) * 8) = make_uint2(pk0, pk1);

  int lab = label[row];  // half-wave uniform
  int base = lab * 128 + lh * 4;
  atomicAdd(&shg[base + 0], x0);
  atomicAdd(&shg[base + 1], x1);
  atomicAdd(&shg[base + 2], x2);
  atomicAdd(&shg[base + 3], x3);
  if (lh == 0) atomicAdd(&shc[lab], 1);
  __syncthreads();
  // 4-way split target: per-address global chain is 256, not 1024
  atomicAdd(&gh4[(blockIdx.x & 3) * 256 + tid], shg[tid]);
  if (tid < 2) atomicAdd(&cnt[tid], shc[tid]);
}

// 4 MFMA chains (independent ILP) + streaming exp epilogue for one 16-col group.
__device__ __forceinline__ void consume(const short8 af[4][4], short8 b0, short8 b1,
                                        short8 b2, short8 b3, float m0,
                                        float Z[4][4], float U[4][4], float V0[4][4]) {
#pragma unroll
  for (int s = 0; s < 4; ++s) {
    float4v c = {0.f, 0.f, 0.f, 0.f};
    c = __builtin_amdgcn_mfma_f32_16x16x32_bf16(af[s][0], b0, c, 0, 0, 0);
    c = __builtin_amdgcn_mfma_f32_16x16x32_bf16(af[s][1], b1, c, 0, 0, 0);
    c = __builtin_amdgcn_mfma_f32_16x16x32_bf16(af[s][2], b2, c, 0, 0, 0);
    c = __builtin_amdgcn_mfma_f32_16x16x32_bf16(af[s][3], b3, c, 0, 0, 0);
#pragma unroll
    for (int r = 0; r < 4; ++r) {  // C/D: col=lane&15, row=quad*4+r (m89)
      float l = c[r], e = EXP2(l);          // log2-domain, |l| <= 20.6: fp32-safe
      Z[s][r] += e;
      U[s][r] = fmaf(e, l, U[s][r]);
      V0[s][r] = fmaf(m0, e, V0[s][r]);
    }
  }
}

// K3: barrier-free flash-style Gram-row reductions. No LDS: xnbF (2MB) is
// L2-resident and fragment-ordered, so A and B fragments are direct coalesced
// global loads. 64 output rows per wave (4 row-sets) halves B redundancy vs the
// old 32-row waves; manual 1-deep prefetch hides L1/L2 latency under MFMA+exp.
__global__ __launch_bounds__(256, 3) void k_main(const short* __restrict__ xnbF,
                                                 const int* __restrict__ label,
                                                 const float* __restrict__ mf,
                                                 const float* __restrict__ scale,
                                                 float* __restrict__ Zr,
                                                 float* __restrict__ Ur,
                                                 float* __restrict__ Vr) {
  int tid = threadIdx.x, wave = tid >> 6, lane = tid & 63;
  int quad = lane >> 4, col = lane & 15;
  int rbI = blockIdx.x >> 5;   // 0..31: 256-row block
  int sl = blockIdx.x & 31;    // 0..31: 256-col slice
  float se2 = __expf(scale[0]) * L2E;  // exp(scale)*log2(e): log2-domain logits

  const short8* F = (const short8*)xnbF;  // indexed by 16B chunk

  // A fragments: 4 row-sets of 16 rows; rows rbI*256 + wave*64 + s*16 + col
  int gA = rbI * 16 + wave * 4;
  short8 af[4][4];
#pragma unroll
  for (int s = 0; s < 4; ++s)
#pragma unroll
    for (int t = 0; t < 4; ++t) {
      short8 a = F[(size_t)(gA + s) * 256 + t * 64 + lane];
#pragma unroll
      for (int i = 0; i < 8; ++i) a[i] = f2bf(bf2f(a[i]) * se2);
      af[s][t] = a;
    }

  float Z[4][4] = {}, U[4][4] = {}, V0[4][4] = {};

  int gB0 = sl * 16;  // 16 column groups of 16
  const short8* FB = F + (size_t)gB0 * 256 + lane;

  // prefetch group 0
  short8 a0 = FB[0], a1 = FB[64], a2 = FB[128], a3 = FB[192];
  float am = mf[gB0 * 16 + col];
  for (int gg = 0; gg < 16; ++gg) {
    short8 b0 = a0, b1 = a1, b2 = a2, b3 = a3;
    float bm = am;
    if (gg < 15) {  // issue next group's loads before consuming current
      const short8* np = FB + (size_t)(gg + 1) * 256;
      a0 = np[0]; a1 = np[64]; a2 = np[128]; a3 = np[192];
      am = mf[(gB0 + gg + 1) * 16 + col];
    }
    consume(af, b0, b1, b2, b3, bm, Z, U, V0);
  }

  // reduce across the 16 column-lanes sharing each output row
#pragma unroll
  for (int s = 0; s < 4; ++s)
#pragma unroll
    for (int r = 0; r < 4; ++r)
#pragma unroll
      for (int off = 1; off < 16; off <<= 1) {
        Z[s][r] += __shfl_xor(Z[s][r], off);
        U[s][r] += __shfl_xor(U[s][r], off);
        V0[s][r] += __shfl_xor(V0[s][r], off);
      }
  if (col == 0) {
    int rowb = rbI * 256 + wave * 64;
#pragma unroll
    for (int s = 0; s < 4; ++s)
#pragma unroll
      for (int r = 0; r < 4; ++r) {
        int row = rowb + s * 16 + quad * 4 + r;
        int lab = label[row];
        float v = (lab == 0) ? V0[s][r] : (Z[s][r] - V0[s][r]);
        atomicAdd(&Zr[row], Z[s][r]);
        atomicAdd(&Ur[row], U[s][r] * LN2);  // log2-domain -> nats
        atomicAdd(&Vr[row], v);
      }
  }
}

// K4: per-row loss; S,T via closed-form dots with class sums (re-normalizes x
// from data directly — no f32 xnf copy needed). 1024 blocks x 8 rows.
__global__ __launch_bounds__(256) void k_final(const float* __restrict__ data,
                                               const int* __restrict__ label,
                                               const float* __restrict__ scale,
                                               const float* __restrict__ gh4,
                                               const int* __restrict__ cnt,
                                               const float* __restrict__ Zr,
                                               const float* __restrict__ Ur,
                                               const float* __restrict__ Vr,
                                               float* __restrict__ out) {
  __shared__ float hsum[256];
  __shared__ float bsum[8];
  int tid = threadIdx.x, wave = tid >> 6, lane = tid & 63;
  int lh = lane & 31, rsel = lane >> 5;
  hsum[tid] = gh4[tid] + gh4[256 + tid] + gh4[512 + tid] + gh4[768 + tid];
  __syncthreads();

  float se = __expf(scale[0]);
  float c0 = (float)cnt[0], c1 = (float)cnt[1];
  int row = blockIdx.x * 8 + wave * 2 + rsel;
  float4 v = *(const float4*)&data[row * DD + lh * 4];
  float ss = v.x * v.x + v.y * v.y + v.z * v.z + v.w * v.w;
#pragma unroll
  for (int off = 16; off; off >>= 1) ss += __shfl_xor(ss, off);
  float rn = 1.f / fmaxf(sqrtf(ss), 1e-12f);

  float4 h0 = *(const float4*)&hsum[lh * 4];
  float4 h1 = *(const float4*)&hsum[128 + lh * 4];
  int lab = label[row];
  float sg = v.x * (h0.x + h1.x) + v.y * (h0.y + h1.y) +
             v.z * (h0.z + h1.z) + v.w * (h0.w + h1.w);
  float sh_ = (lab == 0)
                  ? (v.x * h0.x + v.y * h0.y + v.z * h0.z + v.w * h0.w)
                  : (v.x * h1.x + v.y * h1.y + v.z * h1.z + v.w * h1.w);
#pragma unroll
  for (int off = 16; off; off >>= 1) {
    sg += __shfl_xor(sg, off);
    sh_ += __shfl_xor(sh_, off);
  }
  if (lh == 0) {
    float cc = (lab == 0) ? c0 : c1;
    float a = __expf(1.f / cc);
    float Zq = cc * a + ((float)BS - cc);
    float S = se * sg * rn, T = se * sh_ * rn;
    float Zv = Zr[row], Uv = Ur[row], Vv = Vr[row];
    // loss_i = a/Zq - (S+(a-1)T)/Zq + U/Z - V/(c*Z)   (M_i, log Zq cancelled)
    bsum[wave * 2 + rsel] =
        a / Zq - (S + (a - 1.f) * T) / Zq + Uv / Zv - Vv / (cc * Zv);
  }
  __syncthreads();
  if (tid == 0) {
    float s = 0.f;
#pragma unroll
    for (int i = 0; i < 8; ++i) s += bsum[i];
    atomicAdd(out, s * (0.5f / (float)BS));
  }
}

extern "C" void kernel_launch(void* const* d_in, const int* in_sizes, int n_in,
                              void* d_out, int out_size, void* d_ws, size_t ws_size,
                              hipStream_t stream) {
  const float* data = (const float*)d_in[0];
  const float* scale = (const float*)d_in[1];
  const int* label = (const int*)d_in[2];
  char* ws = (char*)d_ws;
  // ws layout (bytes):
  //   0        xnbF bf16 fragment-order [8192*128]   2 MB
  //   2097152  Zr   f32 [8192]
  //   2129920  Ur   f32 [8192]
  //   2162688  Vr   f32 [8192]
  //   2195456  gh4  f32 [4][256]  (4-way split class sums)
  //   2199552  cnt  int [2]
  //   2199560  mf   f32 [8192]
  char* xnbF = ws;
  float* Zr = (float*)(ws + 2097152);
  float* Ur = (float*)(ws + 2129920);
  float* Vr = (float*)(ws + 2162688);
  float* gh4 = (float*)(ws + 2195456);
  int* cnt = (int*)(ws + 2199552);
  float* mf = (float*)(ws + 2199560);

  // gh4+cnt only (4104 B); Zr/Ur/Vr/mf + d_out are initialized inside k_norm
  hipMemsetAsync(ws + 2195456, 0, 4104, stream);

  k_norm<<<1024, 256, 0, stream>>>(data, label, xnbF, gh4, cnt, Zr, Ur, Vr, mf,
                                   (float*)d_out);
  k_main<<<1024, 256, 0, stream>>>((const short*)xnbF, label, mf, scale, Zr, Ur, Vr);
  k_final<<<1024, 256, 0, stream>>>(data, label, scale, gh4, cnt, Zr, Ur, Vr,
                                    (float*)d_out);
}

// Round 3
// 120.852 us; speedup vs baseline: 1.1860x; 1.1860x over previous
//
#include <hip/hip_runtime.h>
#include <stdint.h>

#define BS 8192
#define DD 128
#define L2E 1.4426950408889634f
#define LN2 0.6931471805599453f

typedef __attribute__((ext_vector_type(8))) short short8;
typedef __attribute__((ext_vector_type(4))) float float4v;

#if __has_builtin(__builtin_amdgcn_exp2f)
#define EXP2(x) __builtin_amdgcn_exp2f(x)
#else
#define EXP2(x) exp2f(x)
#endif

__device__ __forceinline__ float bf2f(short s) {
  union { unsigned u; float f; } c;
  c.u = ((unsigned)(unsigned short)s) << 16;
  return c.f;
}
__device__ __forceinline__ short f2bf(float f) {
  union { float f; unsigned u; } c; c.f = f;
  unsigned u = c.u + 0x7FFFu + ((c.u >> 16) & 1u);
  return (short)(u >> 16);
}

// Fragment-ordered bf16 layout ("xnbF"): 16-byte chunk index for (row, kc):
//   chunk(row,kc) = (row>>4)*256 + (kc>>2)*64 + (kc&3)*16 + (row&15)
// A wave load F[g*256 + t*64 + lane] gives lane (quad=lane>>4, col=lane&15) the
// 8 bf16 of row g*16+col, k-chunk 4t+quad — exactly the mfma_f32_16x16x32_bf16
// A/B fragment layout. Both A and B fragments are single coalesced 1KB wave
// loads from L2; k_main has no LDS and no barriers.

// K1: normalize rows -> xnbF, per-class column sums (register-accumulated, then
// LDS, then 4-way-split global atomics: chain 64), counts, mask mf, zero-init.
// 256 blocks x 32 rows (4 iterations of 2 rows per wave via float4 half-waves).
__global__ __launch_bounds__(256) void k_norm(const float* __restrict__ data,
                                              const int* __restrict__ label,
                                              char* __restrict__ xnbF,
                                              float* __restrict__ gh4,
                                              int* __restrict__ cnt4,
                                              float* __restrict__ Zr,
                                              float* __restrict__ Ur,
                                              float* __restrict__ Vr,
                                              float* __restrict__ mf) {
  __shared__ float shg[256];
  __shared__ int shc[2];
  int tid = threadIdx.x, wave = tid >> 6, lane = tid & 63;
  int lh = lane & 31, rsel = lane >> 5;
  if (tid < 2) shc[tid] = 0;
  shg[tid] = 0.f;
  int rowbase = blockIdx.x * 32;
  if (tid < 32) {  // zero this block's accumulator rows (workspace is poisoned)
    int row = rowbase + tid;
    Zr[row] = 0.f; Ur[row] = 0.f; Vr[row] = 0.f;
    mf[row] = (label[row] == 0) ? 1.f : 0.f;
  }
  __syncthreads();

  float a00 = 0.f, a01 = 0.f, a02 = 0.f, a03 = 0.f;  // class-0 column partials
  float a10 = 0.f, a11 = 0.f, a12 = 0.f, a13 = 0.f;  // class-1
  int c0 = 0, c1 = 0;
#pragma unroll
  for (int it = 0; it < 4; ++it) {
    int row = rowbase + it * 8 + wave * 2 + rsel;
    float4 v = *(const float4*)&data[row * DD + lh * 4];  // 16B/lane coalesced
    float ss = v.x * v.x + v.y * v.y + v.z * v.z + v.w * v.w;
#pragma unroll
    for (int off = 16; off; off >>= 1) ss += __shfl_xor(ss, off);  // 32-lane
    float rn = 1.f / fmaxf(sqrtf(ss), 1e-12f);  // F.normalize eps clamp
    float x0 = v.x * rn, x1 = v.y * rn, x2 = v.z * rn, x3 = v.w * rn;

    unsigned pk0 = (unsigned)(unsigned short)f2bf(x0) |
                   ((unsigned)(unsigned short)f2bf(x1) << 16);
    unsigned pk1 = (unsigned)(unsigned short)f2bf(x2) |
                   ((unsigned)(unsigned short)f2bf(x3) << 16);
    int kc = lh >> 1;
    size_t chunk = (size_t)(row >> 4) * 256 + (size_t)(kc >> 2) * 64 +
                   (size_t)(kc & 3) * 16 + (row & 15);
    *(uint2*)(xnbF + chunk * 16 + (lh & 1) * 8) = make_uint2(pk0, pk1);

    int lab = label[row];  // half-wave uniform
    if (lab == 0) {
      a00 += x0; a01 += x1; a02 += x2; a03 += x3;
      if (lh == 0) c0++;
    } else {
      a10 += x0; a11 += x1; a12 += x2; a13 += x3;
      if (lh == 0) c1++;
    }
  }
  int base = lh * 4;  // 8 colliders per address (4 waves x 2 halves)
  atomicAdd(&shg[base + 0], a00); atomicAdd(&shg[base + 1], a01);
  atomicAdd(&shg[base + 2], a02); atomicAdd(&shg[base + 3], a03);
  atomicAdd(&shg[128 + base + 0], a10); atomicAdd(&shg[128 + base + 1], a11);
  atomicAdd(&shg[128 + base + 2], a12); atomicAdd(&shg[128 + base + 3], a13);
  if (lh == 0) { atomicAdd(&shc[0], c0); atomicAdd(&shc[1], c1); }
  __syncthreads();
  // 4-way-split targets: per-address global atomic chain is 64, not 256
  atomicAdd(&gh4[(blockIdx.x & 3) * 256 + tid], shg[tid]);
  if (tid < 2) atomicAdd(&cnt4[(blockIdx.x & 3) * 2 + tid], shc[tid]);
}

// K3: barrier-free flash-style Gram-row reductions, fully inlined (round-2
// post-mortem: passing af[][]/Z[][] as function array params escaped them to
// scratch -> VGPR 84 + 20MB scratch writes). All state in named vectors with
// compile-time indices; launch_bounds(256,2) caps VGPR at 256 so nothing
// spills (~160 live regs -> 3 waves/SIMD).
__global__ __launch_bounds__(256, 2) void k_main(const short* __restrict__ xnbF,
                                                 const int* __restrict__ label,
                                                 const float* __restrict__ mf,
                                                 const float* __restrict__ scale,
                                                 float* __restrict__ Zr,
                                                 float* __restrict__ Ur,
                                                 float* __restrict__ Vr) {
  int tid = threadIdx.x, wave = tid >> 6, lane = tid & 63;
  int quad = lane >> 4, col = lane & 15;
  int rbI = blockIdx.x >> 5;   // 0..31: 256-row block
  int sl = blockIdx.x & 31;    // 0..31: 256-col slice
  float se2 = __expf(scale[0]) * L2E;  // exp(scale)*log2(e): log2-domain logits

  const short8* F = (const short8*)xnbF;  // indexed by 16B chunk

  // A fragments: 4 row-sets of 16 rows (64 rows/wave); scaled by se2 once.
  int gA = rbI * 16 + wave * 4;
  short8 af[4][4];
#pragma unroll
  for (int s = 0; s < 4; ++s)
#pragma unroll
    for (int t = 0; t < 4; ++t) {
      short8 a = F[(size_t)(gA + s) * 256 + t * 64 + lane];
#pragma unroll
      for (int i = 0; i < 8; ++i) a[i] = f2bf(bf2f(a[i]) * se2);
      af[s][t] = a;
    }

  float4v Zc0 = {0.f,0.f,0.f,0.f}, Zc1 = Zc0, Zc2 = Zc0, Zc3 = Zc0;
  float4v Uc0 = Zc0, Uc1 = Zc0, Uc2 = Zc0, Uc3 = Zc0;
  float4v Vc0 = Zc0, Vc1 = Zc0, Vc2 = Zc0, Vc3 = Zc0;

  const short8* FB = F + (size_t)(sl * 16) * 256 + lane;
  // 1-deep manual prefetch of the 4 B k-chunks + mask
  short8 n0 = FB[0], n1 = FB[64], n2 = FB[128], n3 = FB[192];
  float nm = mf[sl * 256 + col];

  for (int gg = 0; gg < 16; ++gg) {
    short8 b0 = n0, b1 = n1, b2 = n2, b3 = n3;
    float bm = nm;
    if (gg < 15) {  // issue next group's loads before consuming current
      const short8* np = FB + (size_t)(gg + 1) * 256;
      n0 = np[0]; n1 = np[64]; n2 = np[128]; n3 = np[192];
      nm = mf[sl * 256 + (gg + 1) * 16 + col];
    }
#define ROWSET(s, Zc, Uc, Vc)                                                  \
    {                                                                          \
      float4v c = {0.f, 0.f, 0.f, 0.f};                                        \
      c = __builtin_amdgcn_mfma_f32_16x16x32_bf16(af[s][0], b0, c, 0, 0, 0);   \
      c = __builtin_amdgcn_mfma_f32_16x16x32_bf16(af[s][1], b1, c, 0, 0, 0);   \
      c = __builtin_amdgcn_mfma_f32_16x16x32_bf16(af[s][2], b2, c, 0, 0, 0);   \
      c = __builtin_amdgcn_mfma_f32_16x16x32_bf16(af[s][3], b3, c, 0, 0, 0);   \
      _Pragma("unroll")                                                        \
      for (int r = 0; r < 4; ++r) { /* C/D: col=lane&15, row=quad*4+r (m89) */ \
        float l = c[r], e = EXP2(l); /* log2-domain, |l|<=20.6: fp32-safe */   \
        Zc[r] += e;                                                            \
        Uc[r] = fmaf(e, l, Uc[r]);                                             \
        Vc[r] = fmaf(bm, e, Vc[r]);                                            \
      }                                                                        \
    }
    ROWSET(0, Zc0, Uc0, Vc0)
    ROWSET(1, Zc1, Uc1, Vc1)
    ROWSET(2, Zc2, Uc2, Vc2)
    ROWSET(3, Zc3, Uc3, Vc3)
#undef ROWSET
  }

  // reduce across the 16 column-lanes sharing each output row, then atomics
#define EMIT(s, Zc, Uc, Vc)                                                    \
  {                                                                            \
    _Pragma("unroll")                                                          \
    for (int r = 0; r < 4; ++r) {                                              \
      float z = Zc[r], u = Uc[r], v0 = Vc[r];                                  \
      _Pragma("unroll")                                                        \
      for (int off = 1; off < 16; off <<= 1) {                                 \
        z += __shfl_xor(z, off);                                               \
        u += __shfl_xor(u, off);                                               \
        v0 += __shfl_xor(v0, off);                                             \
      }                                                                        \
      if (col == 0) {                                                          \
        int row = rbI * 256 + wave * 64 + s * 16 + quad * 4 + r;               \
        int lab = label[row];                                                  \
        float v = (lab == 0) ? v0 : (z - v0);                                  \
        atomicAdd(&Zr[row], z);                                                \
        atomicAdd(&Ur[row], u * LN2); /* log2-domain -> nats */                \
        atomicAdd(&Vr[row], v);                                                \
      }                                                                        \
    }                                                                          \
  }
  EMIT(0, Zc0, Uc0, Vc0)
  EMIT(1, Zc1, Uc1, Vc1)
  EMIT(2, Zc2, Uc2, Vc2)
  EMIT(3, Zc3, Uc3, Vc3)
#undef EMIT
}

// K4: per-row loss; S,T via closed-form dots with class sums (re-normalizes
// from data; no f32 copy). 256 blocks x 32 rows; per-block NON-atomic partial.
__global__ __launch_bounds__(256) void k_final(const float* __restrict__ data,
                                               const int* __restrict__ label,
                                               const float* __restrict__ scale,
                                               const float* __restrict__ gh4,
                                               const int* __restrict__ cnt4,
                                               const float* __restrict__ Zr,
                                               const float* __restrict__ Ur,
                                               const float* __restrict__ Vr,
                                               float* __restrict__ partial) {
  __shared__ float hsum[256];
  __shared__ float bsum[4];
  int tid = threadIdx.x, wave = tid >> 6, lane = tid & 63;
  int lh = lane & 31, rsel = lane >> 5;
  hsum[tid] = gh4[tid] + gh4[256 + tid] + gh4[512 + tid] + gh4[768 + tid];
  __syncthreads();

  float se = __expf(scale[0]);
  float c0 = (float)(cnt4[0] + cnt4[2] + cnt4[4] + cnt4[6]);
  float c1 = (float)(cnt4[1] + cnt4[3] + cnt4[5] + cnt4[7]);
  float4 h0 = *(const float4*)&hsum[lh * 4];
  float4 h1 = *(const float4*)&hsum[128 + lh * 4];

  float local = 0.f;
#pragma unroll
  for (int it = 0; it < 4; ++it) {
    int row = blockIdx.x * 32 + it * 8 + wave * 2 + rsel;
    float4 v = *(const float4*)&data[row * DD + lh * 4];
    float ss = v.x * v.x + v.y * v.y + v.z * v.z + v.w * v.w;
#pragma unroll
    for (int off = 16; off; off >>= 1) ss += __shfl_xor(ss, off);
    float rn = 1.f / fmaxf(sqrtf(ss), 1e-12f);

    int lab = label[row];
    float sg = v.x * (h0.x + h1.x) + v.y * (h0.y + h1.y) +
               v.z * (h0.z + h1.z) + v.w * (h0.w + h1.w);
    float sh_ = (lab == 0)
                    ? (v.x * h0.x + v.y * h0.y + v.z * h0.z + v.w * h0.w)
                    : (v.x * h1.x + v.y * h1.y + v.z * h1.z + v.w * h1.w);
#pragma unroll
    for (int off = 16; off; off >>= 1) {
      sg += __shfl_xor(sg, off);
      sh_ += __shfl_xor(sh_, off);
    }
    if (lh == 0) {
      float cc = (lab == 0) ? c0 : c1;
      float a = __expf(1.f / cc);
      float Zq = cc * a + ((float)BS - cc);
      float S = se * sg * rn, T = se * sh_ * rn;
      float Zv = Zr[row], Uv = Ur[row], Vv = Vr[row];
      // loss_i = a/Zq - (S+(a-1)T)/Zq + U/Z - V/(c*Z)  (M_i, log Zq cancelled)
      local += a / Zq - (S + (a - 1.f) * T) / Zq + Uv / Zv - Vv / (cc * Zv);
    }
  }
  // local is nonzero only on lanes 0 and 32; full-wave reduce is safe
#pragma unroll
  for (int off = 32; off; off >>= 1) local += __shfl_xor(local, off);
  if (lane == 0) bsum[wave] = local;
  __syncthreads();
  if (tid == 0) partial[blockIdx.x] = bsum[0] + bsum[1] + bsum[2] + bsum[3];
}

// K5: single-block sum of 256 partials; plain store (no atomics, no init).
__global__ __launch_bounds__(256) void k_sum(const float* __restrict__ partial,
                                             float* __restrict__ out) {
  __shared__ float bsum[4];
  int tid = threadIdx.x, wave = tid >> 6, lane = tid & 63;
  float v = partial[tid];
#pragma unroll
  for (int off = 32; off; off >>= 1) v += __shfl_xor(v, off);
  if (lane == 0) bsum[wave] = v;
  __syncthreads();
  if (tid == 0)
    out[0] = (bsum[0] + bsum[1] + bsum[2] + bsum[3]) * (0.5f / (float)BS);
}

extern "C" void kernel_launch(void* const* d_in, const int* in_sizes, int n_in,
                              void* d_out, int out_size, void* d_ws, size_t ws_size,
                              hipStream_t stream) {
  const float* data = (const float*)d_in[0];
  const float* scale = (const float*)d_in[1];
  const int* label = (const int*)d_in[2];
  char* ws = (char*)d_ws;
  // ws layout (bytes):
  //   0        xnbF bf16 fragment-order [8192*128]   2 MB
  //   2097152  Zr   f32 [8192]
  //   2129920  Ur   f32 [8192]
  //   2162688  Vr   f32 [8192]
  //   2195456  gh4  f32 [4][256]  (4-way split class sums)
  //   2199552  cnt4 int [8]       (4-way split class counts)
  //   2199584  mf   f32 [8192]
  //   2232352  partial f32 [256]
  char* xnbF = ws;
  float* Zr = (float*)(ws + 2097152);
  float* Ur = (float*)(ws + 2129920);
  float* Vr = (float*)(ws + 2162688);
  float* gh4 = (float*)(ws + 2195456);
  int* cnt4 = (int*)(ws + 2199552);
  float* mf = (float*)(ws + 2199584);
  float* partial = (float*)(ws + 2232352);

  // gh4+cnt4 only (4128 B); Zr/Ur/Vr/mf zeroed in k_norm; partial fully
  // written by k_final; out plain-stored by k_sum.
  hipMemsetAsync(ws + 2195456, 0, 4128, stream);

  k_norm<<<256, 256, 0, stream>>>(data, label, xnbF, gh4, cnt4, Zr, Ur, Vr, mf);
  k_main<<<1024, 256, 0, stream>>>((const short*)xnbF, label, mf, scale, Zr, Ur, Vr);
  k_final<<<256, 256, 0, stream>>>(data, label, scale, gh4, cnt4, Zr, Ur, Vr, partial);
  k_sum<<<1, 256, 0, stream>>>(partial, (float*)d_out);
}